// Round 3
// baseline (365.701 us; speedup 1.0000x reference)
//
#include <hip/hip_runtime.h>
#include <math.h>

typedef _Float16 f16;
typedef _Float16 f16x2 __attribute__((ext_vector_type(2)));
typedef _Float16 f16x4 __attribute__((ext_vector_type(4)));
typedef _Float16 f16x8 __attribute__((ext_vector_type(8)));
typedef __fp16 fp16x2 __attribute__((ext_vector_type(2)));
typedef float f32x4 __attribute__((ext_vector_type(4)));
typedef float f32x16 __attribute__((ext_vector_type(16)));
typedef unsigned int u32;

#define T_ 2048
#define H_ 16
#define C_ 2048

__device__ __forceinline__ void gload_lds16(const f16* g, f16* l) {
  __builtin_amdgcn_global_load_lds((const __attribute__((address_space(1))) u32*)g,
                                   (__attribute__((address_space(3))) u32*)l, 16, 0, 0);
}

__device__ __forceinline__ u32 pkk(float x, float y) {
  union { fp16x2 h; u32 u; } z;
  z.h = __builtin_amdgcn_cvt_pkrtz(x, y);
  return z.u;
}

// ---------------- cast fp32 -> fp16 ----------------
__global__ __launch_bounds__(256) void cast_all_kernel(
    const float* __restrict__ x, const float* __restrict__ wq, const float* __restrict__ wk,
    const float* __restrict__ wv, const float* __restrict__ wo,
    f16* __restrict__ xh, f16* __restrict__ wqh, f16* __restrict__ wkh,
    f16* __restrict__ wvh, f16* __restrict__ woh) {
  int b = blockIdx.x;
  const float* src; f16* dst; size_t off;
  if (b < 8192) { src = x; dst = xh; off = (size_t)b * 1024; }
  else {
    int s = (b - 8192) >> 12, bb = (b - 8192) & 4095;
    off = (size_t)bb * 1024;
    if (s == 0) { src = wq; dst = wqh; }
    else if (s == 1) { src = wk; dst = wkh; }
    else if (s == 2) { src = wv; dst = wvh; }
    else { src = wo; dst = woh; }
  }
  size_t i = off + (size_t)threadIdx.x * 4;
  float4 v = *(const float4*)&src[i];
  f16x4 o; o[0] = (f16)v.x; o[1] = (f16)v.y; o[2] = (f16)v.z; o[3] = (f16)v.w;
  *(f16x4*)&dst[i] = o;
}

// ---------------- 128x128 GEMM body ----------------
template<typename OutT>
__device__ __forceinline__ void gemm128(const f16* __restrict__ A, const f16* __restrict__ Bm,
                                        OutT* __restrict__ Cm, f16* As, f16* Bs,
                                        int brow, int bcol) {
  const int K = 2048, N = 2048;
  const int tid = threadIdx.x, l = tid & 63, w = tid >> 6;
  const int lr = l & 15, lg = l >> 4;
  const int wr = (w >> 1) * 64, wc = (w & 1) * 64;
  const int srow = l >> 2, scol = (l & 3) * 8;
  const f16* gA0 = A + (size_t)(brow + w * 32 + srow) * K + scol;
  const f16* gA1 = gA0 + (size_t)16 * K;
  const f16* gB0 = Bm + (size_t)(bcol + w * 32 + srow) * K + scol;
  const f16* gB1 = gB0 + (size_t)16 * K;
  f16* lA0 = &As[(w * 32 + 0) * 32];
  f16* lA1 = &As[(w * 32 + 16) * 32];
  f16* lB0 = &Bs[(w * 32 + 0) * 32];
  f16* lB1 = &Bs[(w * 32 + 16) * 32];
  f32x4 acc[4][4] = {};
  for (int kt = 0; kt < K; kt += 32) {
    gload_lds16(gA0 + kt, lA0);
    gload_lds16(gA1 + kt, lA1);
    gload_lds16(gB0 + kt, lB0);
    gload_lds16(gB1 + kt, lB1);
    __syncthreads();
    f16x8 af[4], bf[4];
#pragma unroll
    for (int m = 0; m < 4; ++m) af[m] = *(const f16x8*)&As[(wr + m * 16 + lr) * 32 + lg * 8];
#pragma unroll
    for (int n = 0; n < 4; ++n) bf[n] = *(const f16x8*)&Bs[(wc + n * 16 + lr) * 32 + lg * 8];
#pragma unroll
    for (int m = 0; m < 4; ++m)
#pragma unroll
      for (int n = 0; n < 4; ++n)
        acc[m][n] = __builtin_amdgcn_mfma_f32_16x16x32_f16(af[m], bf[n], acc[m][n], 0, 0, 0);
    __syncthreads();
  }
#pragma unroll
  for (int m = 0; m < 4; ++m) {
    int row0 = brow + wr + m * 16 + lg * 4;
#pragma unroll
    for (int n = 0; n < 4; ++n) {
      int col = bcol + wc + n * 16 + lr;
#pragma unroll
      for (int j = 0; j < 4; ++j)
        Cm[(size_t)(row0 + j) * N + col] = (OutT)acc[m][n][j];
    }
  }
}

__global__ __launch_bounds__(256) void gemm_qkv_kernel(
    const f16* __restrict__ A, const f16* __restrict__ Wq, const f16* __restrict__ Wk,
    const f16* __restrict__ Wv, f16* __restrict__ Qo, f16* __restrict__ Ko, f16* __restrict__ Vo) {
  __shared__ f16 As[4096], Bs[4096];
  const f16* Bm; f16* Cm;
  if (blockIdx.z == 0) { Bm = Wq; Cm = Qo; }
  else if (blockIdx.z == 1) { Bm = Wk; Cm = Ko; }
  else { Bm = Wv; Cm = Vo; }
  gemm128<f16>(A, Bm, Cm, As, Bs, blockIdx.x * 128, blockIdx.y * 128);
}

__global__ __launch_bounds__(256) void gemm_out_kernel(
    const f16* __restrict__ A, const f16* __restrict__ Wo, float* __restrict__ Cm) {
  __shared__ f16 As[4096], Bs[4096];
  gemm128<float>(A, Wo, Cm, As, Bs, blockIdx.x * 128, blockIdx.y * 128);
}

// ---------------- QK-norm + RoPE (q and k in one launch) ----------------
// q gets extra sqrt(D)=11.3137 fold: 45.2548*11.3137 = 512 exactly.
__global__ __launch_bounds__(256) void normrope_kernel(f16* __restrict__ qp, f16* __restrict__ kp,
                                                       const float* __restrict__ qk_scale) {
  int w = threadIdx.x >> 6, l = threadIdx.x & 63;
  f16* q = blockIdx.y == 0 ? qp : kp;
  float fac = blockIdx.y == 0 ? 512.0f : 45.254833995939045f;
  int row = blockIdx.x * 4 + w;          // row = (b*T + t)*H + h
  int t = (row >> 4) & (T_ - 1);
  size_t base = (size_t)row * 128;
  float x1 = (float)q[base + l], x2 = (float)q[base + 64 + l];
  float ss = x1 * x1 + x2 * x2;
#pragma unroll
  for (int m = 1; m < 64; m <<= 1) ss += __shfl_xor(ss, m);
  float inv = 1.0f / fmaxf(sqrtf(ss), 1e-12f);
  float sc1 = qk_scale[l] * fac;
  float sc2 = qk_scale[l + 64] * fac;
  float s1 = x1 * inv * sc1, s2 = x2 * inv * sc2;
  float invf = exp2f(-(float)l * 0.20762050593046013f);
  float ang = (float)t * invf;
  float sn, cs; sincosf(ang, &sn, &cs);
  q[base + l] = (f16)(s1 * cs + s2 * sn);
  q[base + 64 + l] = (f16)(-s1 * sn + s2 * cs);
}

// ---------------- causal flash attention, 32x32 MFMA, dbuf ----------------
#define KSTR 132
#define VSTR 68
__global__ __launch_bounds__(256, 2) void attn_kernel(
    const f16* __restrict__ Q, const f16* __restrict__ K, const f16* __restrict__ V,
    f16* __restrict__ Y) {
  __shared__ f16 Ks[2][64 * KSTR];
  __shared__ f16 Vt[2][128 * VSTR];
  const int tid = threadIdx.x, l = tid & 63, w = tid >> 6;
  const int lq = l & 31, hi = l >> 5;
  const int id = blockIdx.x;
  const int bh = id & 31;
  const int qi = id >> 5;
  const int qx = qi < 8 ? qi : 23 - qi;   // pair long+short blocks per CU (RR heuristic)
  const int qb = qx * 128;
  const int b = bh >> 4, h = bh & 15;
  const size_t hb = ((size_t)b * T_ * H_ + h) * 128;
  const int qw = qb + w * 32;
  const int q = qw + lq;

  f16x8 qB[8];
  {
    const f16* qp = Q + hb + (size_t)q * 2048 + hi * 8;
#pragma unroll
    for (int dc = 0; dc < 8; ++dc) qB[dc] = *(const f16x8*)(qp + dc * 16);
  }

  const int ntiles = qb / 64 + 2;
  const int lastit = qb / 64 + (w >> 1);

  const int krow = tid >> 2, kcg = (tid & 3) * 32;
  const int vp2 = tid & 31, vdg = (tid >> 5) * 8;

  f16x8 kr0, kr1, kr2, kr3, vr0a, vr1a, vr0b, vr1b;
  auto load_tile = [&](int kv0) {
    const f16* ksrc = K + hb + (size_t)(kv0 + krow) * 2048 + kcg;
    kr0 = *(const f16x8*)(ksrc);
    kr1 = *(const f16x8*)(ksrc + 8);
    kr2 = *(const f16x8*)(ksrc + 16);
    kr3 = *(const f16x8*)(ksrc + 24);
    const f16* vsrc = V + hb + (size_t)(kv0 + 2 * vp2) * 2048;
    vr0a = *(const f16x8*)(vsrc + vdg);
    vr1a = *(const f16x8*)(vsrc + 2048 + vdg);
    vr0b = *(const f16x8*)(vsrc + vdg + 64);
    vr1b = *(const f16x8*)(vsrc + 2048 + vdg + 64);
  };
  auto write_tile = [&](int buf) {
    f16* kd = &Ks[buf][krow * KSTR + kcg];
    *(f16x8*)(kd) = kr0; *(f16x8*)(kd + 8) = kr1;
    *(f16x8*)(kd + 16) = kr2; *(f16x8*)(kd + 24) = kr3;
#pragma unroll
    for (int j = 0; j < 8; ++j) {
      union { f16x2 h2; u32 u; } p0, p1;
      p0.h2[0] = vr0a[j]; p0.h2[1] = vr1a[j];
      *(u32*)&Vt[buf][(vdg + j) * VSTR + 2 * vp2] = p0.u;
      p1.h2[0] = vr0b[j]; p1.h2[1] = vr1b[j];
      *(u32*)&Vt[buf][(vdg + 64 + j) * VSTR + 2 * vp2] = p1.u;
    }
  };

  load_tile(0);
  write_tile(0);
  __syncthreads();

  float mreg = -INFINITY, rsum = 0.f;
  f32x16 o0 = {}, o1 = {}, o2 = {}, o3 = {};

  for (int it = 0; it < ntiles; ++it) {
    const int cur = it & 1;
    const int kv0 = it * 64;
    const bool havenext = (it + 1 < ntiles);
    if (havenext) load_tile(kv0 + 64);   // issue early; consumed after barrier (T14)

    if (it <= lastit) {
      // ---- QK^T: D[kv][q], kv in two 32-halves ----
      f32x16 s0 = {}, s1 = {};
      const f16* kb = &Ks[cur][lq * KSTR + hi * 8];
#pragma unroll
      for (int dc = 0; dc < 8; ++dc) {
        f16x8 kf = *(const f16x8*)(kb + dc * 16);
        s0 = __builtin_amdgcn_mfma_f32_32x32x16_f16(kf, qB[dc], s0, 0, 0, 0);
      }
      const f16* kb1 = kb + 32 * KSTR;
#pragma unroll
      for (int dc = 0; dc < 8; ++dc) {
        f16x8 kf = *(const f16x8*)(kb1 + dc * 16);
        s1 = __builtin_amdgcn_mfma_f32_32x32x16_f16(kf, qB[dc], s1, 0, 0, 0);
      }
      if (it == lastit) {   // diagonal tile: causal mask
#pragma unroll
        for (int r = 0; r < 16; ++r) {
          int crow = (r & 3) + 8 * (r >> 2) + 4 * hi;
          s0[r] = (kv0 + crow <= q) ? s0[r] : -INFINITY;
          s1[r] = (kv0 + 32 + crow <= q) ? s1[r] : -INFINITY;
        }
      }
      // ---- online softmax (row q = lq, pair lanes l & l^32) ----
      float pm = s0[0];
#pragma unroll
      for (int r = 1; r < 16; ++r) pm = fmaxf(pm, s0[r]);
#pragma unroll
      for (int r = 0; r < 16; ++r) pm = fmaxf(pm, s1[r]);
      pm = fmaxf(pm, __shfl_xor(pm, 32));
      if (__any(pm > mreg + 8.0f)) {      // defer-max (T13)
        float mn = fmaxf(mreg, pm);
        float al = __expf(mreg - mn);
        o0 *= al; o1 *= al; o2 *= al; o3 *= al;
        rsum *= al; mreg = mn;
      }
      float sum = 0.f;
#pragma unroll
      for (int r = 0; r < 16; ++r) { float e = __expf(s0[r] - mreg); s0[r] = e; sum += e; }
#pragma unroll
      for (int r = 0; r < 16; ++r) { float e = __expf(s1[r] - mreg); s1[r] = e; sum += e; }
      sum += __shfl_xor(sum, 32);
      rsum += sum;
      // ---- P -> f16 B-fragments in-register (cvt_pk + shfl_xor 32), then PV ----
#define PVSTEP(SV, BB, KS)                                                          \
      {                                                                             \
        u32 a0 = pkk(SV[8*BB+0], SV[8*BB+1]);                                       \
        u32 a1 = pkk(SV[8*BB+2], SV[8*BB+3]);                                       \
        u32 b0 = pkk(SV[8*BB+4], SV[8*BB+5]);                                       \
        u32 b1 = pkk(SV[8*BB+6], SV[8*BB+7]);                                       \
        u32 r0 = __shfl_xor(hi ? a0 : b0, 32);                                      \
        u32 r1 = __shfl_xor(hi ? a1 : b1, 32);                                      \
        union { u32 u[4]; f16x8 v; } pf;                                            \
        pf.u[0] = hi ? r0 : a0; pf.u[1] = hi ? r1 : a1;                             \
        pf.u[2] = hi ? b0 : r0; pf.u[3] = hi ? b1 : r1;                             \
        const f16* vb = &Vt[cur][lq * VSTR + (KS) * 16 + hi * 8];                   \
        o0 = __builtin_amdgcn_mfma_f32_32x32x16_f16(*(const f16x8*)(vb), pf.v, o0, 0, 0, 0); \
        o1 = __builtin_amdgcn_mfma_f32_32x32x16_f16(*(const f16x8*)(vb + 32 * VSTR), pf.v, o1, 0, 0, 0); \
        o2 = __builtin_amdgcn_mfma_f32_32x32x16_f16(*(const f16x8*)(vb + 64 * VSTR), pf.v, o2, 0, 0, 0); \
        o3 = __builtin_amdgcn_mfma_f32_32x32x16_f16(*(const f16x8*)(vb + 96 * VSTR), pf.v, o3, 0, 0, 0); \
      }
      PVSTEP(s0, 0, 0)
      PVSTEP(s0, 1, 1)
      PVSTEP(s1, 0, 2)
      PVSTEP(s1, 1, 3)
#undef PVSTEP
    }
    __syncthreads();
    if (havenext) {
      write_tile(cur ^ 1);
      __syncthreads();
    }
  }

  // ---- epilogue ----
  float inv = 1.0f / rsum;
  const size_t yb = ((size_t)(b * T_ + q)) * 2048 + h * 128;
#define OSTORE(OV, DT)                                                   \
  {                                                                      \
    _Pragma("unroll")                                                    \
    for (int g = 0; g < 4; ++g) {                                        \
      f16x4 pk;                                                          \
      pk[0] = (f16)(OV[g * 4 + 0] * inv); pk[1] = (f16)(OV[g * 4 + 1] * inv); \
      pk[2] = (f16)(OV[g * 4 + 2] * inv); pk[3] = (f16)(OV[g * 4 + 3] * inv); \
      *(f16x4*)&Y[yb + (DT) * 32 + g * 8 + 4 * hi] = pk;                 \
    }                                                                    \
  }
  OSTORE(o0, 0) OSTORE(o1, 1) OSTORE(o2, 2) OSTORE(o3, 3)
#undef OSTORE
}

// ---------------- host ----------------
extern "C" void kernel_launch(void* const* d_in, const int* in_sizes, int n_in,
                              void* d_out, int out_size, void* d_ws, size_t ws_size,
                              hipStream_t stream) {
  const float* x  = (const float*)d_in[0];
  const float* Wq = (const float*)d_in[1];
  const float* Wk = (const float*)d_in[2];
  const float* Wv = (const float*)d_in[3];
  const float* Wo = (const float*)d_in[4];
  const float* qk_scale = (const float*)d_in[5];
  float* out = (float*)d_out;
  char* ws = (char*)d_ws;

  f16* xh  = (f16*)(ws);
  f16* wqh = (f16*)(ws + 16777216);
  f16* wkh = (f16*)(ws + 25165824);
  f16* wvh = (f16*)(ws + 33554432);
  f16* woh = (f16*)(ws + 41943040);
  f16* qh  = (f16*)(ws + 50331648);
  f16* kh  = (f16*)(ws + 67108864);
  f16* vh  = (f16*)(ws + 83886080);
  f16* yh  = (f16*)(ws + 100663296);

  cast_all_kernel<<<dim3(24576), dim3(256), 0, stream>>>(x, Wq, Wk, Wv, Wo, xh, wqh, wkh, wvh, woh);
  gemm_qkv_kernel<<<dim3(32, 16, 3), dim3(256), 0, stream>>>(xh, wqh, wkh, wvh, qh, kh, vh);
  normrope_kernel<<<dim3(16384, 2), dim3(256), 0, stream>>>(qh, kh, qk_scale);
  attn_kernel<<<dim3(512), dim3(256), 0, stream>>>(qh, kh, vh, yh);
  gemm_out_kernel<<<dim3(32, 16), dim3(256), 0, stream>>>(yh, woh, out);
}